// Round 9
// baseline (177.151 us; speedup 1.0000x reference)
//
#include <hip/hip_runtime.h>
#include <hip/hip_bf16.h>

typedef float f32x4 __attribute__((ext_vector_type(4)));
typedef short bf16x8 __attribute__((ext_vector_type(8)));
typedef unsigned int u32x2 __attribute__((ext_vector_type(2)));

#define NPAIRS 16384
#define NROWS  32768
#define D      128
#define NCOL   512     // live gate cols (quad-interleaved: n' = 4*j + quad, j<128)
#define MROWS  64
#define FEW    5
#define NN     200
#define STEPS  4
#define JCH    25
#define SA_STR 392     // sA row stride in shorts: q(128)|hq(128)|r(128)|pad(8)
#define SL     (NCOL * 32)

// workspace offsets (bytes)
#define WS_WGP  0           // bf16 [12][512][32] = 393216
#define WS_BP   393216      // f32 [512]
#define WS_SG   395264      // f32 [5][128]
#define WS_MS   397824      // f32 [128]
#define WS_PART 398336      // f32 [125][256] = 128000
#define WS_GQ   526336      // bf16 [32768][512] = 33554432 (q@Wq cache)

static __device__ __forceinline__ unsigned short f2bf(float f) {
  union { float f; unsigned u; } v; v.f = f;
  unsigned r = v.u + 0x7FFF + ((v.u >> 16) & 1);
  return (unsigned short)(r >> 16);
}
static __device__ __forceinline__ float bf2f(unsigned short h) {
  union { unsigned u; float f; } v; v.u = ((unsigned)h) << 16;
  return v.f;
}
static __device__ __forceinline__ float sigm(float x) {
  return 1.0f / (1.0f + __expf(-x));
}
static __device__ __forceinline__ float tanh_(float x) {
  float e = __expf(-2.0f * fabsf(x));
  float t = (1.0f - e) / (1.0f + e);
  return x >= 0.f ? t : -t;
}

// ---- K1: weight panel (12 slices: q|hq|r) + bias + support gather, merged ----
__global__ void prep_and_gather(const float* __restrict__ wih, const float* __restrict__ whh,
                                const float* __restrict__ bih, const float* __restrict__ bhh,
                                const int* __restrict__ sp, const float* __restrict__ emb,
                                unsigned short* __restrict__ Wgp, float* __restrict__ bp,
                                float* __restrict__ part) {
  int b = blockIdx.x;
  if (b < 768) {
    int idx = b * 256 + threadIdx.x;     // < 196608 = 12*512*32
    if (idx < NCOL) {
      int j = idx >> 2, q = idx & 3;
      bp[idx] = bih[q * 256 + j] + bhh[q * 256 + j];
    }
    int ks = idx >> 14;
    int n  = (idx >> 5) & 511;
    int ki = idx & 31;
    int k  = ks * 32 + ki;
    int j = n >> 2, q = n & 3;
    int rowg = q * 256 + j;
    float v = (k < 128) ? wih[rowg * 128 + k] : whh[rowg * 256 + (k - 128)];
    Wgp[idx] = f2bf(v);
  } else {
    int g = b - 768;
    int f = g / JCH, cj = g % JCH;
    int k = threadIdx.x;
    int sel = k >> 7, kk = k & 127;
    float a = 0.f;
#pragma unroll
    for (int jj = 0; jj < 8; ++jj) {
      int sym = sp[(f * NN + cj * 8 + jj) * 2 + sel];
      a += emb[(size_t)sym * D + kk];
    }
    part[(f * JCH + cj) * 256 + k] = a;
  }
}

// ---- K2: support stage 2: reduce partials + MLP + LN ----
__global__ void support_kernel(
    const float* __restrict__ part,
    const float* __restrict__ gw, const float* __restrict__ gb,
    const float* __restrict__ p1w, const float* __restrict__ p1b,
    const float* __restrict__ p2w, const float* __restrict__ p2b,
    const float* __restrict__ lng, const float* __restrict__ lnb,
    float* __restrict__ sg_out, float* __restrict__ ms_out) {
  __shared__ float S[FEW][256];
  __shared__ float sup[FEW][128];
  __shared__ float h1[FEW][256];
  __shared__ float xx[FEW][128];
  __shared__ float sgS[FEW][128];
  __shared__ float mv[FEW][2];
  int tid = threadIdx.x;
  for (int i = tid; i < FEW * 256; i += 256) {
    int f = i >> 8, k = i & 255;
    float a = 0.f;
#pragma unroll
    for (int c = 0; c < JCH; ++c) a += part[(f * JCH + c) * 256 + k];
    S[f][k] = a;
  }
  __syncthreads();
  for (int i = tid; i < FEW * 128; i += 256) {
    int f = i >> 7, o = i & 127;
    float a = 0.f;
    for (int k = 0; k < 256; ++k) a += S[f][k] * gw[o * 256 + k];
    sup[f][o] = tanh_((a + 200.f * gb[o]) * 0.2f);
  }
  __syncthreads();
  for (int i = tid; i < FEW * 256; i += 256) {
    int f = i >> 8, p = i & 255;
    float a = p1b[p];
    for (int o = 0; o < 128; ++o) a += sup[f][o] * p1w[p * 128 + o];
    h1[f][p] = fmaxf(a, 0.f);
  }
  __syncthreads();
  for (int i = tid; i < FEW * 128; i += 256) {
    int f = i >> 7, o = i & 127;
    float a = p2b[o];
    for (int p = 0; p < 256; ++p) a += h1[f][p] * p2w[o * 256 + p];
    xx[f][o] = a + sup[f][o];
  }
  __syncthreads();
  if (tid < FEW) {
    float mu = 0.f;
    for (int k = 0; k < 128; ++k) mu += xx[tid][k];
    mu *= (1.f / 128.f);
    float var = 0.f;
    for (int k = 0; k < 128; ++k) { float dd = xx[tid][k] - mu; var += dd * dd; }
    var *= (1.f / 128.f);
    mv[tid][0] = mu;
    mv[tid][1] = rsqrtf(var + 1e-5f);
  }
  __syncthreads();
  for (int i = tid; i < FEW * 128; i += 256) {
    int f = i >> 7, o = i & 127;
    float v = lng[o] * (xx[f][o] - mv[f][0]) * mv[f][1] + lnb[o];
    sgS[f][o] = v;
    sg_out[i] = v;
  }
  __syncthreads();
  if (tid < 128) {
    float a = 0.f;
    for (int f = 0; f < FEW; ++f) a += sgS[f][tid];
    ms_out[tid] = a * 0.2f;
  }
}

// ---- K3: fused query path. R7 structure (2 blocks/CU, 64 VGPR + 64 AGPR = 128).
// GQ variant: q@Wq computed once (step 0), cached bf16 in workspace, re-read
// steps 1-3 (same-thread RAW across >=2 barriers) -> steps 1-3 run slices 4..11
// only: 28 total slices vs 40. Runtime ks loop (NEVER unrolled - R5/R6 spill). ----
template <bool GQ>
__global__ __launch_bounds__(512, 4) void fused_query(
    const int* __restrict__ qp, const float* __restrict__ emb,
    const unsigned short* __restrict__ Wgp, const float* __restrict__ bp,
    const float* __restrict__ sgw, const float* __restrict__ msw,
    unsigned int* __restrict__ gqw, float* __restrict__ out) {
  __shared__ __align__(16) unsigned short sA[MROWS][SA_STR];  // q|hq|r, 50176 B
  __shared__ unsigned short sC[MROWS][130];                   // c bf16, 16640 B
  __shared__ float sSg[FEW][132];
  __shared__ __align__(16) float sBias[NCOL];
  __shared__ float sMs[128];

  int tid = threadIdx.x;
  int w = tid >> 6, lane = tid & 63;
  int l15 = lane & 15, l4 = lane >> 4;
  int w16 = w * 16;
  int row0 = blockIdx.x * MROWS;

  for (int i = tid; i < MROWS * 32; i += 512) {
    int r = i >> 5, c4 = i & 31;
    int sym = qp[row0 + r];
    f32x4 v = *(const f32x4*)(emb + (size_t)sym * D + c4 * 4);
    int k = c4 * 4;
    sA[r][k + 0] = f2bf(v[0]); sA[r][k + 1] = f2bf(v[1]);
    sA[r][k + 2] = f2bf(v[2]); sA[r][k + 3] = f2bf(v[3]);
  }
  for (int i = tid; i < MROWS * 128; i += 512) sC[i >> 7][i & 127] = 0;
  for (int i = tid; i < FEW * 128; i += 512) sSg[i >> 7][i & 127] = sgw[i];
  if (tid < NCOL) sBias[tid] = bp[tid];
  if (tid < 128) sMs[tid] = msw[tid];
  __syncthreads();

  const unsigned short* wptr = Wgp + (size_t)(w * 64 + l15) * 32 + l4 * 8;

  for (int s = 0; s < STEPS; ++s) {
    // ---- gates GEMM; GQ: steps>=1 skip q slices (cached) ----
    f32x4 acc[4][4];
#pragma unroll
    for (int gt = 0; gt < 4; ++gt)
#pragma unroll
      for (int bt = 0; bt < 4; ++bt) acc[gt][bt] = {0.f, 0.f, 0.f, 0.f};
    int kbeg = (GQ && s > 0) ? 4 : 0;
    int kend = (s == 0) ? 4 : 12;
    for (int ks = kbeg; ks < kend; ++ks) {
      const unsigned short* wk = wptr + (size_t)ks * SL;
      bf16x8 bfrag[4];
#pragma unroll
      for (int gt = 0; gt < 4; ++gt) bfrag[gt] = *(const bf16x8*)(wk + gt * 512);
      bf16x8 afrag[4];
#pragma unroll
      for (int bt = 0; bt < 4; ++bt)
        afrag[bt] = *(const bf16x8*)&sA[bt * 16 + l15][ks * 32 + l4 * 8];
#pragma unroll
      for (int gt = 0; gt < 4; ++gt)
#pragma unroll
        for (int bt = 0; bt < 4; ++bt)
          acc[gt][bt] = __builtin_amdgcn_mfma_f32_16x16x32_bf16(
              bfrag[gt], afrag[bt], acc[gt][bt], 0, 0, 0);
    }
    __syncthreads();  // GEMM reads of sA done before hq overwrite

    // ---- EW: acc f32x4 IS (i,f,g,o) for (row=bt*16+l15, j=w16+gt*4+l4).
    // gq loads batched 8 cells per half; sched_barrier caps hoisting (+16 VGPR max).
#pragma unroll
    for (int hf = 0; hf < 2; ++hf) {
      u32x2 gql[2][4];
      if (GQ && s > 0) {
#pragma unroll
        for (int g2 = 0; g2 < 2; ++g2) {
          int gt = hf * 2 + g2;
          int j = w16 + gt * 4 + l4;
#pragma unroll
          for (int bt = 0; bt < 4; ++bt)
            gql[g2][bt] = *(const u32x2*)(gqw + (size_t)(row0 + bt * 16 + l15) * 256 + 2 * j);
        }
      }
#pragma unroll
      for (int g2 = 0; g2 < 2; ++g2) {
        int gt = hf * 2 + g2;
        int j = w16 + gt * 4 + l4;
        f32x4 bi = *(const f32x4*)&sBias[4 * j];
#pragma unroll
        for (int bt = 0; bt < 4; ++bt) {
          int row = bt * 16 + l15;
          f32x4 g = acc[gt][bt];
          if (GQ) {
            if (s == 0) {  // store gq = q@Wq (pre-bias), bf16-packed
              u32x2 pk;
              pk[0] = (unsigned)f2bf(g[0]) | ((unsigned)f2bf(g[1]) << 16);
              pk[1] = (unsigned)f2bf(g[2]) | ((unsigned)f2bf(g[3]) << 16);
              *(u32x2*)(gqw + (size_t)(row0 + row) * 256 + 2 * j) = pk;
            } else {       // add cached gq
              u32x2 pk = gql[g2][bt];
              g[0] += bf2f((unsigned short)(pk[0] & 0xFFFFu));
              g[1] += bf2f((unsigned short)(pk[0] >> 16));
              g[2] += bf2f((unsigned short)(pk[1] & 0xFFFFu));
              g[3] += bf2f((unsigned short)(pk[1] >> 16));
            }
          }
          float gi = g[0] + bi[0];
          float gf = g[1] + bi[1];
          float gg = g[2] + bi[2];
          float go = g[3] + bi[3];
          float c_old = bf2f(sC[row][j]);
          float c_new = sigm(gf) * c_old + sigm(gi) * tanh_(gg);
          sC[row][j] = f2bf(c_new);
          float hl = sigm(go) * tanh_(c_new);
          float hqv = bf2f(sA[row][j]) + hl;  // q + h_lstm
          sA[row][128 + j] = f2bf(hqv);
        }
      }
      __builtin_amdgcn_sched_barrier(0);
    }
    __syncthreads();

    // ---- ATTN: logits + softmax + r (chunk-swizzled) ----
    if (s < STEPS - 1) {
      int arow = tid >> 3, part = tid & 7;
      int ck = ((part + arow) & 7) * 16;
      bf16x8 h0 = *(const bf16x8*)&sA[arow][128 + ck];
      bf16x8 h1 = *(const bf16x8*)&sA[arow][128 + ck + 8];
      float hv[16];
#pragma unroll
      for (int e = 0; e < 8; ++e) {
        hv[e] = bf2f((unsigned short)h0[e]);
        hv[8 + e] = bf2f((unsigned short)h1[e]);
      }
      float lg[FEW];
#pragma unroll
      for (int ss = 0; ss < FEW; ++ss) {
        float a = 0.f;
#pragma unroll
        for (int e4 = 0; e4 < 4; ++e4) {
          f32x4 sv = *(const f32x4*)&sSg[ss][ck + e4 * 4];
          a += hv[e4 * 4 + 0] * sv[0] + hv[e4 * 4 + 1] * sv[1] +
               hv[e4 * 4 + 2] * sv[2] + hv[e4 * 4 + 3] * sv[3];
        }
        lg[ss] = a;
      }
#pragma unroll
      for (int off = 1; off < 8; off <<= 1)
#pragma unroll
        for (int ss = 0; ss < FEW; ++ss) lg[ss] += __shfl_xor(lg[ss], off, 64);
      float m = lg[0];
#pragma unroll
      for (int ss = 1; ss < FEW; ++ss) m = fmaxf(m, lg[ss]);
      float ev[FEW], tot = 0.f;
#pragma unroll
      for (int ss = 0; ss < FEW; ++ss) { ev[ss] = __expf(lg[ss] - m); tot += ev[ss]; }
      float inv = 1.0f / tot;
      bf16x8 r0, r1;
#pragma unroll
      for (int e = 0; e < 8; ++e) {
        int k0 = ck + e;
        int k1 = ck + 8 + e;
        float rv0 = 0.f, rv1 = 0.f;
#pragma unroll
        for (int ss = 0; ss < FEW; ++ss) {
          rv0 += ev[ss] * sSg[ss][k0];
          rv1 += ev[ss] * sSg[ss][k1];
        }
        r0[e] = (short)f2bf(rv0 * inv);
        r1[e] = (short)f2bf(rv1 * inv);
      }
      *(bf16x8*)&sA[arow][256 + ck] = r0;
      *(bf16x8*)&sA[arow][256 + ck + 8] = r1;
      __syncthreads();
    }
  }

  // ---- output: out[pair] = mean(hq[2p], hq[2p+1]) . mean_support ----
  int pair = tid >> 4, part = tid & 15;
  float accv = 0.f;
#pragma unroll
  for (int kk = 0; kk < 8; ++kk) {
    int k = part * 8 + kk;
    float h0 = bf2f(sA[2 * pair][128 + k]);
    float h1v = bf2f(sA[2 * pair + 1][128 + k]);
    accv += 0.5f * (h0 + h1v) * sMs[k];
  }
#pragma unroll
  for (int off = 1; off < 16; off <<= 1) accv += __shfl_xor(accv, off, 64);
  if (part == 0) out[blockIdx.x * 32 + pair] = accv;
}

extern "C" void kernel_launch(void* const* d_in, const int* in_sizes, int n_in,
                              void* d_out, int out_size, void* d_ws, size_t ws_size,
                              hipStream_t stream) {
  const int*   qp  = (const int*)d_in[0];
  const int*   sp  = (const int*)d_in[1];
  const float* emb = (const float*)d_in[2];
  const float* gw  = (const float*)d_in[3];
  const float* gb  = (const float*)d_in[4];
  const float* p1w = (const float*)d_in[5];
  const float* p1b = (const float*)d_in[6];
  const float* p2w = (const float*)d_in[7];
  const float* p2b = (const float*)d_in[8];
  const float* lng = (const float*)d_in[9];
  const float* lnb = (const float*)d_in[10];
  const float* wih = (const float*)d_in[11];
  const float* whh = (const float*)d_in[12];
  const float* bih = (const float*)d_in[13];
  const float* bhh = (const float*)d_in[14];
  char* ws = (char*)d_ws;
  unsigned short* Wgp = (unsigned short*)(ws + WS_WGP);
  float* bp   = (float*)(ws + WS_BP);
  float* sg   = (float*)(ws + WS_SG);
  float* ms   = (float*)(ws + WS_MS);
  float* part = (float*)(ws + WS_PART);
  unsigned int* gqw = (unsigned int*)(ws + WS_GQ);
  float* out  = (float*)d_out;

  hipLaunchKernelGGL(prep_and_gather, dim3(768 + FEW * JCH), dim3(256), 0, stream,
                     wih, whh, bih, bhh, sp, emb, Wgp, bp, part);
  hipLaunchKernelGGL(support_kernel, dim3(1), dim3(256), 0, stream,
                     part, gw, gb, p1w, p1b, p2w, p2b, lng, lnb, sg, ms);
  bool has_gq = ws_size >= (size_t)WS_GQ + (size_t)NROWS * 512 * 2;
  if (has_gq) {
    fused_query<true><<<dim3(NROWS / MROWS), dim3(512), 0, stream>>>(
        qp, emb, Wgp, bp, sg, ms, gqw, out);
  } else {
    fused_query<false><<<dim3(NROWS / MROWS), dim3(512), 0, stream>>>(
        qp, emb, Wgp, bp, sg, ms, gqw, out);
  }
}

// Round 10
// 132.460 us; speedup vs baseline: 1.3374x; 1.3374x over previous
//
#include <hip/hip_runtime.h>
#include <hip/hip_bf16.h>

typedef float f32x4 __attribute__((ext_vector_type(4)));
typedef short bf16x8 __attribute__((ext_vector_type(8)));

#define NPAIRS 16384
#define NROWS  32768
#define D      128
#define NCOL   512     // live gate cols (quad-interleaved: n' = 4*j + quad, j<128)
#define MROWS  64
#define FEW    5
#define NN     200
#define STEPS  4
#define JCH    25
#define SA_STR 392     // sA row stride in shorts: q(128)|hq(128)|r(128)|pad(8)
#define SL     (NCOL * 32)

// workspace offsets (bytes)
#define WS_WGP  0           // bf16 [12][512][32] = 393216
#define WS_BP   393216      // f32 [512]
#define WS_SG   395264      // f32 [5][128]
#define WS_MS   397824      // f32 [128]
#define WS_PART 398336      // f32 [125][256] = 128000

static __device__ __forceinline__ unsigned short f2bf(float f) {
  union { float f; unsigned u; } v; v.f = f;
  unsigned r = v.u + 0x7FFF + ((v.u >> 16) & 1);
  return (unsigned short)(r >> 16);
}
static __device__ __forceinline__ float bf2f(unsigned short h) {
  union { unsigned u; float f; } v; v.u = ((unsigned)h) << 16;
  return v.f;
}
// rcp-based activations: v_rcp_f32 (~1 ulp) instead of IEEE divide sequence
// (~10 VALU instrs each without -ffast-math). 5 divides/cell -> 5 rcp.
static __device__ __forceinline__ float sigm(float x) {
  float e = __expf(-x);
  return __builtin_amdgcn_rcpf(1.0f + e);
}
static __device__ __forceinline__ float tanh_(float x) {
  float e = __expf(-2.0f * fabsf(x));
  float t = (1.0f - e) * __builtin_amdgcn_rcpf(1.0f + e);
  return x >= 0.f ? t : -t;
}

// ---- K1: weight panel (12 slices: q|hq|r) + bias + support gather, merged ----
__global__ void prep_and_gather(const float* __restrict__ wih, const float* __restrict__ whh,
                                const float* __restrict__ bih, const float* __restrict__ bhh,
                                const int* __restrict__ sp, const float* __restrict__ emb,
                                unsigned short* __restrict__ Wgp, float* __restrict__ bp,
                                float* __restrict__ part) {
  int b = blockIdx.x;
  if (b < 768) {
    int idx = b * 256 + threadIdx.x;     // < 196608 = 12*512*32
    if (idx < NCOL) {
      int j = idx >> 2, q = idx & 3;
      bp[idx] = bih[q * 256 + j] + bhh[q * 256 + j];
    }
    int ks = idx >> 14;
    int n  = (idx >> 5) & 511;
    int ki = idx & 31;
    int k  = ks * 32 + ki;
    int j = n >> 2, q = n & 3;
    int rowg = q * 256 + j;
    float v = (k < 128) ? wih[rowg * 128 + k] : whh[rowg * 256 + (k - 128)];
    Wgp[idx] = f2bf(v);
  } else {
    int g = b - 768;
    int f = g / JCH, cj = g % JCH;
    int k = threadIdx.x;
    int sel = k >> 7, kk = k & 127;
    float a = 0.f;
#pragma unroll
    for (int jj = 0; jj < 8; ++jj) {
      int sym = sp[(f * NN + cj * 8 + jj) * 2 + sel];
      a += emb[(size_t)sym * D + kk];
    }
    part[(f * JCH + cj) * 256 + k] = a;
  }
}

// ---- K2: support stage 2: reduce partials + MLP + LN ----
__global__ void support_kernel(
    const float* __restrict__ part,
    const float* __restrict__ gw, const float* __restrict__ gb,
    const float* __restrict__ p1w, const float* __restrict__ p1b,
    const float* __restrict__ p2w, const float* __restrict__ p2b,
    const float* __restrict__ lng, const float* __restrict__ lnb,
    float* __restrict__ sg_out, float* __restrict__ ms_out) {
  __shared__ float S[FEW][256];
  __shared__ float sup[FEW][128];
  __shared__ float h1[FEW][256];
  __shared__ float xx[FEW][128];
  __shared__ float sgS[FEW][128];
  __shared__ float mv[FEW][2];
  int tid = threadIdx.x;
  for (int i = tid; i < FEW * 256; i += 256) {
    int f = i >> 8, k = i & 255;
    float a = 0.f;
#pragma unroll
    for (int c = 0; c < JCH; ++c) a += part[(f * JCH + c) * 256 + k];
    S[f][k] = a;
  }
  __syncthreads();
  for (int i = tid; i < FEW * 128; i += 256) {
    int f = i >> 7, o = i & 127;
    float a = 0.f;
    for (int k = 0; k < 256; ++k) a += S[f][k] * gw[o * 256 + k];
    sup[f][o] = tanh_((a + 200.f * gb[o]) * 0.2f);
  }
  __syncthreads();
  for (int i = tid; i < FEW * 256; i += 256) {
    int f = i >> 8, p = i & 255;
    float a = p1b[p];
    for (int o = 0; o < 128; ++o) a += sup[f][o] * p1w[p * 128 + o];
    h1[f][p] = fmaxf(a, 0.f);
  }
  __syncthreads();
  for (int i = tid; i < FEW * 128; i += 256) {
    int f = i >> 7, o = i & 127;
    float a = p2b[o];
    for (int p = 0; p < 256; ++p) a += h1[f][p] * p2w[o * 256 + p];
    xx[f][o] = a + sup[f][o];
  }
  __syncthreads();
  if (tid < FEW) {
    float mu = 0.f;
    for (int k = 0; k < 128; ++k) mu += xx[tid][k];
    mu *= (1.f / 128.f);
    float var = 0.f;
    for (int k = 0; k < 128; ++k) { float dd = xx[tid][k] - mu; var += dd * dd; }
    var *= (1.f / 128.f);
    mv[tid][0] = mu;
    mv[tid][1] = rsqrtf(var + 1e-5f);
  }
  __syncthreads();
  for (int i = tid; i < FEW * 128; i += 256) {
    int f = i >> 7, o = i & 127;
    float v = lng[o] * (xx[f][o] - mv[f][0]) * mv[f][1] + lnb[o];
    sgS[f][o] = v;
    sg_out[i] = v;
  }
  __syncthreads();
  if (tid < 128) {
    float a = 0.f;
    for (int f = 0; f < FEW; ++f) a += sgS[f][tid];
    ms_out[tid] = a * 0.2f;
  }
}

// ---- K3: fused query path — R7 structure exactly (2 blocks/CU, 64+64=128 regs,
// runtime ks loop, NEVER unrolled) with rcp-based activations. ----
__global__ __launch_bounds__(512, 4) void fused_query(
    const int* __restrict__ qp, const float* __restrict__ emb,
    const unsigned short* __restrict__ Wgp, const float* __restrict__ bp,
    const float* __restrict__ sgw, const float* __restrict__ msw,
    float* __restrict__ out) {
  __shared__ __align__(16) unsigned short sA[MROWS][SA_STR];  // q|hq|r, 50176 B
  __shared__ unsigned short sC[MROWS][130];                   // c bf16, 16640 B
  __shared__ float sSg[FEW][132];
  __shared__ __align__(16) float sBias[NCOL];
  __shared__ float sMs[128];

  int tid = threadIdx.x;
  int w = tid >> 6, lane = tid & 63;
  int l15 = lane & 15, l4 = lane >> 4;
  int w16 = w * 16;
  int row0 = blockIdx.x * MROWS;

  for (int i = tid; i < MROWS * 32; i += 512) {
    int r = i >> 5, c4 = i & 31;
    int sym = qp[row0 + r];
    f32x4 v = *(const f32x4*)(emb + (size_t)sym * D + c4 * 4);
    int k = c4 * 4;
    sA[r][k + 0] = f2bf(v[0]); sA[r][k + 1] = f2bf(v[1]);
    sA[r][k + 2] = f2bf(v[2]); sA[r][k + 3] = f2bf(v[3]);
  }
  for (int i = tid; i < MROWS * 128; i += 512) sC[i >> 7][i & 127] = 0;
  for (int i = tid; i < FEW * 128; i += 512) sSg[i >> 7][i & 127] = sgw[i];
  if (tid < NCOL) sBias[tid] = bp[tid];
  if (tid < 128) sMs[tid] = msw[tid];
  __syncthreads();

  const unsigned short* wptr = Wgp + (size_t)(w * 64 + l15) * 32 + l4 * 8;

  for (int s = 0; s < STEPS; ++s) {
    // ---- gates GEMM: 4 gate-tiles x 4 row-tiles, runtime-count ks loop ----
    f32x4 acc[4][4];
#pragma unroll
    for (int gt = 0; gt < 4; ++gt)
#pragma unroll
      for (int bt = 0; bt < 4; ++bt) acc[gt][bt] = {0.f, 0.f, 0.f, 0.f};
    int ksmax = (s == 0) ? 4 : 12;  // step 0: hq/r zero — only q contributes
    for (int ks = 0; ks < ksmax; ++ks) {
      const unsigned short* wk = wptr + (size_t)ks * SL;
      bf16x8 bfrag[4];
#pragma unroll
      for (int gt = 0; gt < 4; ++gt) bfrag[gt] = *(const bf16x8*)(wk + gt * 512);
      bf16x8 afrag[4];
#pragma unroll
      for (int bt = 0; bt < 4; ++bt)
        afrag[bt] = *(const bf16x8*)&sA[bt * 16 + l15][ks * 32 + l4 * 8];
#pragma unroll
      for (int gt = 0; gt < 4; ++gt)
#pragma unroll
        for (int bt = 0; bt < 4; ++bt)
          acc[gt][bt] = __builtin_amdgcn_mfma_f32_16x16x32_bf16(
              bfrag[gt], afrag[bt], acc[gt][bt], 0, 0, 0);
    }
    __syncthreads();  // GEMM reads of sA done before hq overwrite

    // ---- EW: acc f32x4 IS (i,f,g,o) for (row=bt*16+l15, j=w16+gt*4+l4) ----
#pragma unroll
    for (int gt = 0; gt < 4; ++gt) {
      int j = w16 + gt * 4 + l4;
      f32x4 bi = *(const f32x4*)&sBias[4 * j];
#pragma unroll
      for (int bt = 0; bt < 4; ++bt) {
        int row = bt * 16 + l15;
        f32x4 g = acc[gt][bt];
        float gi = g[0] + bi[0];
        float gf = g[1] + bi[1];
        float gg = g[2] + bi[2];
        float go = g[3] + bi[3];
        float c_old = bf2f(sC[row][j]);
        float c_new = sigm(gf) * c_old + sigm(gi) * tanh_(gg);
        sC[row][j] = f2bf(c_new);
        float hl = sigm(go) * tanh_(c_new);
        float hqv = bf2f(sA[row][j]) + hl;  // q + h_lstm
        sA[row][128 + j] = f2bf(hqv);
      }
    }
    __syncthreads();

    // ---- ATTN: logits + softmax + r (vectorized, chunk-swizzled) ----
    if (s < STEPS - 1) {
      int arow = tid >> 3, part = tid & 7;
      int ck = ((part + arow) & 7) * 16;
      bf16x8 h0 = *(const bf16x8*)&sA[arow][128 + ck];
      bf16x8 h1 = *(const bf16x8*)&sA[arow][128 + ck + 8];
      float hv[16];
#pragma unroll
      for (int e = 0; e < 8; ++e) {
        hv[e] = bf2f((unsigned short)h0[e]);
        hv[8 + e] = bf2f((unsigned short)h1[e]);
      }
      float lg[FEW];
#pragma unroll
      for (int ss = 0; ss < FEW; ++ss) {
        float a = 0.f;
#pragma unroll
        for (int e4 = 0; e4 < 4; ++e4) {
          f32x4 sv = *(const f32x4*)&sSg[ss][ck + e4 * 4];
          a += hv[e4 * 4 + 0] * sv[0] + hv[e4 * 4 + 1] * sv[1] +
               hv[e4 * 4 + 2] * sv[2] + hv[e4 * 4 + 3] * sv[3];
        }
        lg[ss] = a;
      }
#pragma unroll
      for (int off = 1; off < 8; off <<= 1)
#pragma unroll
        for (int ss = 0; ss < FEW; ++ss) lg[ss] += __shfl_xor(lg[ss], off, 64);
      float m = lg[0];
#pragma unroll
      for (int ss = 1; ss < FEW; ++ss) m = fmaxf(m, lg[ss]);
      float ev[FEW], tot = 0.f;
#pragma unroll
      for (int ss = 0; ss < FEW; ++ss) { ev[ss] = __expf(lg[ss] - m); tot += ev[ss]; }
      float inv = __builtin_amdgcn_rcpf(tot);
      bf16x8 r0, r1;
#pragma unroll
      for (int e = 0; e < 8; ++e) {
        int k0 = ck + e;
        int k1 = ck + 8 + e;
        float rv0 = 0.f, rv1 = 0.f;
#pragma unroll
        for (int ss = 0; ss < FEW; ++ss) {
          rv0 += ev[ss] * sSg[ss][k0];
          rv1 += ev[ss] * sSg[ss][k1];
        }
        r0[e] = (short)f2bf(rv0 * inv);
        r1[e] = (short)f2bf(rv1 * inv);
      }
      *(bf16x8*)&sA[arow][256 + ck] = r0;
      *(bf16x8*)&sA[arow][256 + ck + 8] = r1;
      __syncthreads();
    }
  }

  // ---- output: out[pair] = mean(hq[2p], hq[2p+1]) . mean_support ----
  int pair = tid >> 4, part = tid & 15;
  float accv = 0.f;
#pragma unroll
  for (int kk = 0; kk < 8; ++kk) {
    int k = part * 8 + kk;
    float h0 = bf2f(sA[2 * pair][128 + k]);
    float h1v = bf2f(sA[2 * pair + 1][128 + k]);
    accv += 0.5f * (h0 + h1v) * sMs[k];
  }
#pragma unroll
  for (int off = 1; off < 16; off <<= 1) accv += __shfl_xor(accv, off, 64);
  if (part == 0) out[blockIdx.x * 32 + pair] = accv;
}

extern "C" void kernel_launch(void* const* d_in, const int* in_sizes, int n_in,
                              void* d_out, int out_size, void* d_ws, size_t ws_size,
                              hipStream_t stream) {
  const int*   qp  = (const int*)d_in[0];
  const int*   sp  = (const int*)d_in[1];
  const float* emb = (const float*)d_in[2];
  const float* gw  = (const float*)d_in[3];
  const float* gb  = (const float*)d_in[4];
  const float* p1w = (const float*)d_in[5];
  const float* p1b = (const float*)d_in[6];
  const float* p2w = (const float*)d_in[7];
  const float* p2b = (const float*)d_in[8];
  const float* lng = (const float*)d_in[9];
  const float* lnb = (const float*)d_in[10];
  const float* wih = (const float*)d_in[11];
  const float* whh = (const float*)d_in[12];
  const float* bih = (const float*)d_in[13];
  const float* bhh = (const float*)d_in[14];
  char* ws = (char*)d_ws;
  unsigned short* Wgp = (unsigned short*)(ws + WS_WGP);
  float* bp   = (float*)(ws + WS_BP);
  float* sg   = (float*)(ws + WS_SG);
  float* ms   = (float*)(ws + WS_MS);
  float* part = (float*)(ws + WS_PART);
  float* out  = (float*)d_out;

  hipLaunchKernelGGL(prep_and_gather, dim3(768 + FEW * JCH), dim3(256), 0, stream,
                     wih, whh, bih, bhh, sp, emb, Wgp, bp, part);
  hipLaunchKernelGGL(support_kernel, dim3(1), dim3(256), 0, stream,
                     part, gw, gb, p1w, p1b, p2w, p2b, lng, lnb, sg, ms);
  hipLaunchKernelGGL(fused_query, dim3(NROWS / MROWS), dim3(512), 0, stream,
                     qp, emb, Wgp, bp, sg, ms, out);
}

// Round 11
// 127.764 us; speedup vs baseline: 1.3866x; 1.0368x over previous
//
#include <hip/hip_runtime.h>
#include <hip/hip_bf16.h>

typedef float f32x4 __attribute__((ext_vector_type(4)));
typedef short bf16x8 __attribute__((ext_vector_type(8)));
typedef unsigned int u32x2 __attribute__((ext_vector_type(2)));
typedef unsigned int u32x4 __attribute__((ext_vector_type(4)));

#define NPAIRS 16384
#define NROWS  32768
#define D      128
#define NCOL   512     // live gate cols (quad-interleaved: n' = 4*j + quad, j<128)
#define MROWS  64
#define FEW    5
#define NN     200
#define STEPS  4
#define JCH    25
#define SA_STR 392     // sA row stride in shorts: q(128)|hq(128)|r(128)|pad(8)
#define SL     (NCOL * 32)

// workspace offsets (bytes)
#define WS_WGP  0           // bf16 [12][512][32] = 393216
#define WS_BP   393216      // f32 [512]
#define WS_SG   395264      // f32 [5][128]
#define WS_MS   397824      // f32 [128]
#define WS_PART 398336      // f32 [125][256] = 128000

static __device__ __forceinline__ unsigned cvt_pk_bf16(float lo, float hi) {
  unsigned r;
  asm("v_cvt_pk_bf16_f32 %0, %1, %2" : "=v"(r) : "v"(lo), "v"(hi));
  return r;  // RNE, matches manual round-to-nearest-even
}
static __device__ __forceinline__ unsigned short f2bf(float f) {
  union { float f; unsigned u; } v; v.f = f;
  unsigned r = v.u + 0x7FFF + ((v.u >> 16) & 1);
  return (unsigned short)(r >> 16);
}
static __device__ __forceinline__ float bf2f(unsigned short h) {
  union { unsigned u; float f; } v; v.u = ((unsigned)h) << 16;
  return v.f;
}
// rcp-based activations (R10 win: v_rcp vs IEEE divide sequence)
static __device__ __forceinline__ float sigm(float x) {
  float e = __expf(-x);
  return __builtin_amdgcn_rcpf(1.0f + e);
}
static __device__ __forceinline__ float tanh_(float x) {
  float e = __expf(-2.0f * fabsf(x));
  float t = (1.0f - e) * __builtin_amdgcn_rcpf(1.0f + e);
  return x >= 0.f ? t : -t;
}

// ---- K1: weight panel (12 slices: q|hq|r) + bias + support gather, merged ----
__global__ void prep_and_gather(const float* __restrict__ wih, const float* __restrict__ whh,
                                const float* __restrict__ bih, const float* __restrict__ bhh,
                                const int* __restrict__ sp, const float* __restrict__ emb,
                                unsigned short* __restrict__ Wgp, float* __restrict__ bp,
                                float* __restrict__ part) {
  int b = blockIdx.x;
  if (b < 768) {
    int idx = b * 256 + threadIdx.x;     // < 196608 = 12*512*32
    if (idx < NCOL) {
      int j = idx >> 2, q = idx & 3;
      bp[idx] = bih[q * 256 + j] + bhh[q * 256 + j];
    }
    int ks = idx >> 14;
    int n  = (idx >> 5) & 511;
    int ki = idx & 31;
    int k  = ks * 32 + ki;
    int j = n >> 2, q = n & 3;
    int rowg = q * 256 + j;
    float v = (k < 128) ? wih[rowg * 128 + k] : whh[rowg * 256 + (k - 128)];
    Wgp[idx] = f2bf(v);
  } else {
    int g = b - 768;
    int f = g / JCH, cj = g % JCH;
    int k = threadIdx.x;
    int sel = k >> 7, kk = k & 127;
    float a = 0.f;
#pragma unroll
    for (int jj = 0; jj < 8; ++jj) {
      int sym = sp[(f * NN + cj * 8 + jj) * 2 + sel];
      a += emb[(size_t)sym * D + kk];
    }
    part[(f * JCH + cj) * 256 + k] = a;
  }
}

// ---- K2: support stage 2 — weights STAGED IN LDS (1 CU, 1 wave/SIMD: global
// L2-latency chains were ~35us; LDS-resident operands + f32x4 unroll fix it) ----
__global__ void support_kernel(
    const float* __restrict__ part,
    const float* __restrict__ gw, const float* __restrict__ gb,
    const float* __restrict__ p1w, const float* __restrict__ p1b,
    const float* __restrict__ p2w, const float* __restrict__ p2b,
    const float* __restrict__ lng, const float* __restrict__ lnb,
    float* __restrict__ sg_out, float* __restrict__ ms_out) {
  __shared__ __align__(16) float WBUF[33792];  // 132KB staging (row-padded)
  __shared__ __align__(16) float S[FEW][256];
  __shared__ __align__(16) float sup[FEW][128];
  __shared__ __align__(16) float h1[FEW][256];
  __shared__ float xx[FEW][128];
  __shared__ float sgS[FEW][128];
  __shared__ float mv[FEW][2];
  int tid = threadIdx.x;
  // A: reduce partials
  for (int i = tid; i < FEW * 256; i += 256) {
    int f = i >> 8, k = i & 255;
    float a = 0.f;
#pragma unroll
    for (int c = 0; c < JCH; ++c) a += part[(f * JCH + c) * 256 + k];
    S[f][k] = a;
  }
  // stage gw [128][256] -> WBUF rows of 260 (pad 4: breaks 0-mod-32 bank stride)
  for (int i = tid; i < 128 * 64; i += 256) {
    int o = i >> 6, k4 = i & 63;
    *((f32x4*)&WBUF[o * 260] + k4) = *((const f32x4*)(gw + o * 256) + k4);
  }
  __syncthreads();
  // B: sup = tanh((S @ gw.T + 200*gb)/5)
  for (int i = tid; i < FEW * 128; i += 256) {
    int f = i >> 7, o = i & 127;
    const f32x4* wr = (const f32x4*)&WBUF[o * 260];
    const f32x4* sr = (const f32x4*)&S[f][0];
    float a = 0.f;
#pragma unroll 16
    for (int k4 = 0; k4 < 64; ++k4) {
      f32x4 w = wr[k4], s = sr[k4];
      a += w[0] * s[0] + w[1] * s[1] + w[2] * s[2] + w[3] * s[3];
    }
    sup[f][o] = tanh_((a + 200.f * gb[o]) * 0.2f);
  }
  __syncthreads();
  // stage p1w [256][128] -> rows of 132
  for (int i = tid; i < 256 * 32; i += 256) {
    int p = i >> 5, k4 = i & 31;
    *((f32x4*)&WBUF[p * 132] + k4) = *((const f32x4*)(p1w + p * 128) + k4);
  }
  __syncthreads();
  // C: h1 = relu(sup @ p1w.T + p1b)
  for (int i = tid; i < FEW * 256; i += 256) {
    int f = i >> 8, p = i & 255;
    const f32x4* wr = (const f32x4*)&WBUF[p * 132];
    const f32x4* sr = (const f32x4*)&sup[f][0];
    float a = p1b[p];
#pragma unroll 16
    for (int k4 = 0; k4 < 32; ++k4) {
      f32x4 w = wr[k4], s = sr[k4];
      a += w[0] * s[0] + w[1] * s[1] + w[2] * s[2] + w[3] * s[3];
    }
    h1[f][p] = fmaxf(a, 0.f);
  }
  __syncthreads();
  // stage p2w [128][256] -> rows of 260
  for (int i = tid; i < 128 * 64; i += 256) {
    int o = i >> 6, k4 = i & 63;
    *((f32x4*)&WBUF[o * 260] + k4) = *((const f32x4*)(p2w + o * 256) + k4);
  }
  __syncthreads();
  // D: xx = h1 @ p2w.T + p2b + sup
  for (int i = tid; i < FEW * 128; i += 256) {
    int f = i >> 7, o = i & 127;
    const f32x4* wr = (const f32x4*)&WBUF[o * 260];
    const f32x4* sr = (const f32x4*)&h1[f][0];
    float a = p2b[o];
#pragma unroll 16
    for (int k4 = 0; k4 < 64; ++k4) {
      f32x4 w = wr[k4], s = sr[k4];
      a += w[0] * s[0] + w[1] * s[1] + w[2] * s[2] + w[3] * s[3];
    }
    xx[f][o] = a + sup[f][o];
  }
  __syncthreads();
  if (tid < FEW) {
    float mu = 0.f;
    for (int k = 0; k < 128; ++k) mu += xx[tid][k];
    mu *= (1.f / 128.f);
    float var = 0.f;
    for (int k = 0; k < 128; ++k) { float dd = xx[tid][k] - mu; var += dd * dd; }
    var *= (1.f / 128.f);
    mv[tid][0] = mu;
    mv[tid][1] = rsqrtf(var + 1e-5f);
  }
  __syncthreads();
  for (int i = tid; i < FEW * 128; i += 256) {
    int f = i >> 7, o = i & 127;
    float v = lng[o] * (xx[f][o] - mv[f][0]) * mv[f][1] + lnb[o];
    sgS[f][o] = v;
    sg_out[i] = v;
  }
  __syncthreads();
  if (tid < 128) {
    float a = 0.f;
    for (int f = 0; f < FEW; ++f) a += sgS[f][tid];
    ms_out[tid] = a * 0.2f;
  }
}

// ---- K3: fused query path — R10 structure exactly (2 blocks/CU, 64+64=128 regs,
// runtime ks loop NEVER unrolled) + bias-seeded acc + cvt_pk bf16 conversions ----
__global__ __launch_bounds__(512, 4) void fused_query(
    const int* __restrict__ qp, const float* __restrict__ emb,
    const unsigned short* __restrict__ Wgp, const float* __restrict__ bp,
    const float* __restrict__ sgw, const float* __restrict__ msw,
    float* __restrict__ out) {
  __shared__ __align__(16) unsigned short sA[MROWS][SA_STR];  // q|hq|r, 50176 B
  __shared__ unsigned short sC[MROWS][130];                   // c bf16, 16640 B
  __shared__ float sSg[FEW][132];
  __shared__ __align__(16) float sBias[NCOL];
  __shared__ float sMs[128];

  int tid = threadIdx.x;
  int w = tid >> 6, lane = tid & 63;
  int l15 = lane & 15, l4 = lane >> 4;
  int w16 = w * 16;
  int row0 = blockIdx.x * MROWS;

  for (int i = tid; i < MROWS * 32; i += 512) {
    int r = i >> 5, c4 = i & 31;
    int sym = qp[row0 + r];
    f32x4 v = *(const f32x4*)(emb + (size_t)sym * D + c4 * 4);
    u32x2 pk;
    pk[0] = cvt_pk_bf16(v[0], v[1]);
    pk[1] = cvt_pk_bf16(v[2], v[3]);
    *(u32x2*)&sA[r][c4 * 4] = pk;
  }
  for (int i = tid; i < MROWS * 128; i += 512) sC[i >> 7][i & 127] = 0;
  for (int i = tid; i < FEW * 128; i += 512) sSg[i >> 7][i & 127] = sgw[i];
  if (tid < NCOL) sBias[tid] = bp[tid];
  if (tid < 128) sMs[tid] = msw[tid];
  __syncthreads();

  const unsigned short* wptr = Wgp + (size_t)(w * 64 + l15) * 32 + l4 * 8;

  for (int s = 0; s < STEPS; ++s) {
    // ---- gates GEMM: acc seeded with bias (MFMA C-in is additive) ----
    f32x4 acc[4][4];
#pragma unroll
    for (int gt = 0; gt < 4; ++gt) {
      f32x4 bi = *(const f32x4*)&sBias[4 * (w16 + gt * 4 + l4)];
#pragma unroll
      for (int bt = 0; bt < 4; ++bt) acc[gt][bt] = bi;
    }
    int ksmax = (s == 0) ? 4 : 12;  // step 0: hq/r zero — only q contributes
    for (int ks = 0; ks < ksmax; ++ks) {
      const unsigned short* wk = wptr + (size_t)ks * SL;
      bf16x8 bfrag[4];
#pragma unroll
      for (int gt = 0; gt < 4; ++gt) bfrag[gt] = *(const bf16x8*)(wk + gt * 512);
      bf16x8 afrag[4];
#pragma unroll
      for (int bt = 0; bt < 4; ++bt)
        afrag[bt] = *(const bf16x8*)&sA[bt * 16 + l15][ks * 32 + l4 * 8];
#pragma unroll
      for (int gt = 0; gt < 4; ++gt)
#pragma unroll
        for (int bt = 0; bt < 4; ++bt)
          acc[gt][bt] = __builtin_amdgcn_mfma_f32_16x16x32_bf16(
              bfrag[gt], afrag[bt], acc[gt][bt], 0, 0, 0);
    }
    __syncthreads();  // GEMM reads of sA done before hq overwrite

    // ---- EW: acc f32x4 IS (i,f,g,o)+bias for (row=bt*16+l15, j=w16+gt*4+l4) ----
#pragma unroll
    for (int gt = 0; gt < 4; ++gt) {
      int j = w16 + gt * 4 + l4;
#pragma unroll
      for (int bt = 0; bt < 4; ++bt) {
        int row = bt * 16 + l15;
        f32x4 g = acc[gt][bt];
        float c_old = bf2f(sC[row][j]);
        float c_new = sigm(g[1]) * c_old + sigm(g[0]) * tanh_(g[2]);
        float hl = sigm(g[3]) * tanh_(c_new);
        float hqv = bf2f(sA[row][j]) + hl;  // q + h_lstm
        unsigned pk = cvt_pk_bf16(c_new, hqv);
        sC[row][j] = (unsigned short)pk;
        sA[row][128 + j] = (unsigned short)(pk >> 16);
      }
    }
    __syncthreads();

    // ---- ATTN: logits + softmax + r (vectorized, chunk-swizzled) ----
    if (s < STEPS - 1) {
      int arow = tid >> 3, part = tid & 7;
      int ck = ((part + arow) & 7) * 16;
      bf16x8 h0 = *(const bf16x8*)&sA[arow][128 + ck];
      bf16x8 h1 = *(const bf16x8*)&sA[arow][128 + ck + 8];
      float hv[16];
#pragma unroll
      for (int e = 0; e < 8; ++e) {
        hv[e] = bf2f((unsigned short)h0[e]);
        hv[8 + e] = bf2f((unsigned short)h1[e]);
      }
      float lg[FEW];
#pragma unroll
      for (int ss = 0; ss < FEW; ++ss) {
        float a = 0.f;
#pragma unroll
        for (int e4 = 0; e4 < 4; ++e4) {
          f32x4 sv = *(const f32x4*)&sSg[ss][ck + e4 * 4];
          a += hv[e4 * 4 + 0] * sv[0] + hv[e4 * 4 + 1] * sv[1] +
               hv[e4 * 4 + 2] * sv[2] + hv[e4 * 4 + 3] * sv[3];
        }
        lg[ss] = a;
      }
#pragma unroll
      for (int off = 1; off < 8; off <<= 1)
#pragma unroll
        for (int ss = 0; ss < FEW; ++ss) lg[ss] += __shfl_xor(lg[ss], off, 64);
      float m = lg[0];
#pragma unroll
      for (int ss = 1; ss < FEW; ++ss) m = fmaxf(m, lg[ss]);
      float ev[FEW], tot = 0.f;
#pragma unroll
      for (int ss = 0; ss < FEW; ++ss) { ev[ss] = __expf(lg[ss] - m); tot += ev[ss]; }
      float inv = __builtin_amdgcn_rcpf(tot);
      u32x4 r0u, r1u;
#pragma unroll
      for (int e2 = 0; e2 < 4; ++e2) {
        float v00 = 0.f, v01 = 0.f, v10 = 0.f, v11 = 0.f;
#pragma unroll
        for (int ss = 0; ss < FEW; ++ss) {
          v00 += ev[ss] * sSg[ss][ck + 2 * e2];
          v01 += ev[ss] * sSg[ss][ck + 2 * e2 + 1];
          v10 += ev[ss] * sSg[ss][ck + 8 + 2 * e2];
          v11 += ev[ss] * sSg[ss][ck + 8 + 2 * e2 + 1];
        }
        r0u[e2] = cvt_pk_bf16(v00 * inv, v01 * inv);
        r1u[e2] = cvt_pk_bf16(v10 * inv, v11 * inv);
      }
      // interleave: r0 covers ck..ck+7, r1 covers ck+8..ck+15
      u32x4 lo = {r0u[0], r0u[1], r0u[2], r0u[3]};
      u32x4 hi = {r1u[0], r1u[1], r1u[2], r1u[3]};
      *(u32x4*)&sA[arow][256 + ck] = lo;
      *(u32x4*)&sA[arow][256 + ck + 8] = hi;
      __syncthreads();
    }
  }

  // ---- output: out[pair] = mean(hq[2p], hq[2p+1]) . mean_support ----
  int pair = tid >> 4, part = tid & 15;
  float accv = 0.f;
#pragma unroll
  for (int kk = 0; kk < 8; ++kk) {
    int k = part * 8 + kk;
    float h0 = bf2f(sA[2 * pair][128 + k]);
    float h1v = bf2f(sA[2 * pair + 1][128 + k]);
    accv += 0.5f * (h0 + h1v) * sMs[k];
  }
#pragma unroll
  for (int off = 1; off < 16; off <<= 1) accv += __shfl_xor(accv, off, 64);
  if (part == 0) out[blockIdx.x * 32 + pair] = accv;
}

extern "C" void kernel_launch(void* const* d_in, const int* in_sizes, int n_in,
                              void* d_out, int out_size, void* d_ws, size_t ws_size,
                              hipStream_t stream) {
  const int*   qp  = (const int*)d_in[0];
  const int*   sp  = (const int*)d_in[1];
  const float* emb = (const float*)d_in[2];
  const float* gw  = (const float*)d_in[3];
  const float* gb  = (const float*)d_in[4];
  const float* p1w = (const float*)d_in[5];
  const float* p1b = (const float*)d_in[6];
  const float* p2w = (const float*)d_in[7];
  const float* p2b = (const float*)d_in[8];
  const float* lng = (const float*)d_in[9];
  const float* lnb = (const float*)d_in[10];
  const float* wih = (const float*)d_in[11];
  const float* whh = (const float*)d_in[12];
  const float* bih = (const float*)d_in[13];
  const float* bhh = (const float*)d_in[14];
  char* ws = (char*)d_ws;
  unsigned short* Wgp = (unsigned short*)(ws + WS_WGP);
  float* bp   = (float*)(ws + WS_BP);
  float* sg   = (float*)(ws + WS_SG);
  float* ms   = (float*)(ws + WS_MS);
  float* part = (float*)(ws + WS_PART);
  float* out  = (float*)d_out;

  hipLaunchKernelGGL(prep_and_gather, dim3(768 + FEW * JCH), dim3(256), 0, stream,
                     wih, whh, bih, bhh, sp, emb, Wgp, bp, part);
  hipLaunchKernelGGL(support_kernel, dim3(1), dim3(256), 0, stream,
                     part, gw, gb, p1w, p1b, p2w, p2b, lng, lnb, sg, ms);
  hipLaunchKernelGGL(fused_query, dim3(NROWS / MROWS), dim3(512), 0, stream,
                     qp, emb, Wgp, bp, sg, ms, out);
}

// Round 12
// 121.190 us; speedup vs baseline: 1.4618x; 1.0542x over previous
//
#include <hip/hip_runtime.h>
#include <hip/hip_bf16.h>

typedef float f32x4 __attribute__((ext_vector_type(4)));
typedef short bf16x8 __attribute__((ext_vector_type(8)));

#define NPAIRS 16384
#define NROWS  32768
#define D      128
#define NCOL   512     // live gate cols (quad-interleaved: n' = 4*j + quad, j<128)
#define MROWS  64
#define FEW    5
#define NN     200
#define STEPS  4
#define JCH    25
#define SA_STR 392     // sA row stride in shorts: q(128)|hq(128)|r(128)|pad(8)
#define SL     (NCOL * 32)

// workspace offsets (bytes)
#define WS_WGP  0           // bf16 [12][512][32] = 393216
#define WS_BP   393216      // f32 [512]
#define WS_SG   395264      // f32 [5][128]
#define WS_MS   397824      // f32 [128]
#define WS_PART 398336      // f32 [125][256] = 128000

static __device__ __forceinline__ unsigned short f2bf(float f) {
  union { float f; unsigned u; } v; v.f = f;
  unsigned r = v.u + 0x7FFF + ((v.u >> 16) & 1);
  return (unsigned short)(r >> 16);
}
static __device__ __forceinline__ float bf2f(unsigned short h) {
  union { unsigned u; float f; } v; v.u = ((unsigned)h) << 16;
  return v.f;
}
// rcp-based activations (R10 win: v_rcp vs IEEE divide sequence)
static __device__ __forceinline__ float sigm(float x) {
  float e = __expf(-x);
  return __builtin_amdgcn_rcpf(1.0f + e);
}
static __device__ __forceinline__ float tanh_(float x) {
  float e = __expf(-2.0f * fabsf(x));
  float t = (1.0f - e) * __builtin_amdgcn_rcpf(1.0f + e);
  return x >= 0.f ? t : -t;
}

// ---- K1: weight panel (12 slices: q|hq|r) + bias + support gather, merged ----
__global__ void prep_and_gather(const float* __restrict__ wih, const float* __restrict__ whh,
                                const float* __restrict__ bih, const float* __restrict__ bhh,
                                const int* __restrict__ sp, const float* __restrict__ emb,
                                unsigned short* __restrict__ Wgp, float* __restrict__ bp,
                                float* __restrict__ part) {
  int b = blockIdx.x;
  if (b < 768) {
    int idx = b * 256 + threadIdx.x;     // < 196608 = 12*512*32
    if (idx < NCOL) {
      int j = idx >> 2, q = idx & 3;
      bp[idx] = bih[q * 256 + j] + bhh[q * 256 + j];
    }
    int ks = idx >> 14;
    int n  = (idx >> 5) & 511;
    int ki = idx & 31;
    int k  = ks * 32 + ki;
    int j = n >> 2, q = n & 3;
    int rowg = q * 256 + j;
    float v = (k < 128) ? wih[rowg * 128 + k] : whh[rowg * 256 + (k - 128)];
    Wgp[idx] = f2bf(v);
  } else {
    int g = b - 768;
    int f = g / JCH, cj = g % JCH;
    int k = threadIdx.x;
    int sel = k >> 7, kk = k & 127;
    float a = 0.f;
#pragma unroll
    for (int jj = 0; jj < 8; ++jj) {
      int sym = sp[(f * NN + cj * 8 + jj) * 2 + sel];
      a += emb[(size_t)sym * D + kk];
    }
    part[(f * JCH + cj) * 256 + k] = a;
  }
}

// ---- K2: support stage 2 — weights staged in LDS (R11 win, kept) ----
__global__ void support_kernel(
    const float* __restrict__ part,
    const float* __restrict__ gw, const float* __restrict__ gb,
    const float* __restrict__ p1w, const float* __restrict__ p1b,
    const float* __restrict__ p2w, const float* __restrict__ p2b,
    const float* __restrict__ lng, const float* __restrict__ lnb,
    float* __restrict__ sg_out, float* __restrict__ ms_out) {
  __shared__ __align__(16) float WBUF[33792];  // 132KB staging (row-padded)
  __shared__ __align__(16) float S[FEW][256];
  __shared__ __align__(16) float sup[FEW][128];
  __shared__ __align__(16) float h1[FEW][256];
  __shared__ float xx[FEW][128];
  __shared__ float sgS[FEW][128];
  __shared__ float mv[FEW][2];
  int tid = threadIdx.x;
  for (int i = tid; i < FEW * 256; i += 256) {
    int f = i >> 8, k = i & 255;
    float a = 0.f;
#pragma unroll
    for (int c = 0; c < JCH; ++c) a += part[(f * JCH + c) * 256 + k];
    S[f][k] = a;
  }
  for (int i = tid; i < 128 * 64; i += 256) {
    int o = i >> 6, k4 = i & 63;
    *((f32x4*)&WBUF[o * 260] + k4) = *((const f32x4*)(gw + o * 256) + k4);
  }
  __syncthreads();
  for (int i = tid; i < FEW * 128; i += 256) {
    int f = i >> 7, o = i & 127;
    const f32x4* wr = (const f32x4*)&WBUF[o * 260];
    const f32x4* sr = (const f32x4*)&S[f][0];
    float a = 0.f;
#pragma unroll 16
    for (int k4 = 0; k4 < 64; ++k4) {
      f32x4 w = wr[k4], s = sr[k4];
      a += w[0] * s[0] + w[1] * s[1] + w[2] * s[2] + w[3] * s[3];
    }
    sup[f][o] = tanh_((a + 200.f * gb[o]) * 0.2f);
  }
  __syncthreads();
  for (int i = tid; i < 256 * 32; i += 256) {
    int p = i >> 5, k4 = i & 31;
    *((f32x4*)&WBUF[p * 132] + k4) = *((const f32x4*)(p1w + p * 128) + k4);
  }
  __syncthreads();
  for (int i = tid; i < FEW * 256; i += 256) {
    int f = i >> 8, p = i & 255;
    const f32x4* wr = (const f32x4*)&WBUF[p * 132];
    const f32x4* sr = (const f32x4*)&sup[f][0];
    float a = p1b[p];
#pragma unroll 16
    for (int k4 = 0; k4 < 32; ++k4) {
      f32x4 w = wr[k4], s = sr[k4];
      a += w[0] * s[0] + w[1] * s[1] + w[2] * s[2] + w[3] * s[3];
    }
    h1[f][p] = fmaxf(a, 0.f);
  }
  __syncthreads();
  for (int i = tid; i < 128 * 64; i += 256) {
    int o = i >> 6, k4 = i & 63;
    *((f32x4*)&WBUF[o * 260] + k4) = *((const f32x4*)(p2w + o * 256) + k4);
  }
  __syncthreads();
  for (int i = tid; i < FEW * 128; i += 256) {
    int f = i >> 7, o = i & 127;
    const f32x4* wr = (const f32x4*)&WBUF[o * 260];
    const f32x4* sr = (const f32x4*)&h1[f][0];
    float a = p2b[o];
#pragma unroll 16
    for (int k4 = 0; k4 < 64; ++k4) {
      f32x4 w = wr[k4], s = sr[k4];
      a += w[0] * s[0] + w[1] * s[1] + w[2] * s[2] + w[3] * s[3];
    }
    xx[f][o] = a + sup[f][o];
  }
  __syncthreads();
  if (tid < FEW) {
    float mu = 0.f;
    for (int k = 0; k < 128; ++k) mu += xx[tid][k];
    mu *= (1.f / 128.f);
    float var = 0.f;
    for (int k = 0; k < 128; ++k) { float dd = xx[tid][k] - mu; var += dd * dd; }
    var *= (1.f / 128.f);
    mv[tid][0] = mu;
    mv[tid][1] = rsqrtf(var + 1e-5f);
  }
  __syncthreads();
  for (int i = tid; i < FEW * 128; i += 256) {
    int f = i >> 7, o = i & 127;
    float v = lng[o] * (xx[f][o] - mv[f][0]) * mv[f][1] + lnb[o];
    sgS[f][o] = v;
    sg_out[i] = v;
  }
  __syncthreads();
  if (tid < 128) {
    float a = 0.f;
    for (int f = 0; f < FEW; ++f) a += sgS[f][tid];
    ms_out[tid] = a * 0.2f;
  }
}

// ---- K3: fused query path — byte-exact R10 (79.7us proven: 2 blocks/CU,
// 64 VGPR + 64 AGPR = 128, runtime ks loop NEVER unrolled, rcp activations).
// R11's bundled EW/ATTN cvt_pk + bias-seed changes regressed (conflicts 2x) — reverted. ----
__global__ __launch_bounds__(512, 4) void fused_query(
    const int* __restrict__ qp, const float* __restrict__ emb,
    const unsigned short* __restrict__ Wgp, const float* __restrict__ bp,
    const float* __restrict__ sgw, const float* __restrict__ msw,
    float* __restrict__ out) {
  __shared__ __align__(16) unsigned short sA[MROWS][SA_STR];  // q|hq|r, 50176 B
  __shared__ unsigned short sC[MROWS][130];                   // c bf16, 16640 B
  __shared__ float sSg[FEW][132];
  __shared__ __align__(16) float sBias[NCOL];
  __shared__ float sMs[128];

  int tid = threadIdx.x;
  int w = tid >> 6, lane = tid & 63;
  int l15 = lane & 15, l4 = lane >> 4;
  int w16 = w * 16;
  int row0 = blockIdx.x * MROWS;

  for (int i = tid; i < MROWS * 32; i += 512) {
    int r = i >> 5, c4 = i & 31;
    int sym = qp[row0 + r];
    f32x4 v = *(const f32x4*)(emb + (size_t)sym * D + c4 * 4);
    int k = c4 * 4;
    sA[r][k + 0] = f2bf(v[0]); sA[r][k + 1] = f2bf(v[1]);
    sA[r][k + 2] = f2bf(v[2]); sA[r][k + 3] = f2bf(v[3]);
  }
  for (int i = tid; i < MROWS * 128; i += 512) sC[i >> 7][i & 127] = 0;
  for (int i = tid; i < FEW * 128; i += 512) sSg[i >> 7][i & 127] = sgw[i];
  if (tid < NCOL) sBias[tid] = bp[tid];
  if (tid < 128) sMs[tid] = msw[tid];
  __syncthreads();

  const unsigned short* wptr = Wgp + (size_t)(w * 64 + l15) * 32 + l4 * 8;

  for (int s = 0; s < STEPS; ++s) {
    // ---- gates GEMM: 4 gate-tiles x 4 row-tiles, runtime-count ks loop ----
    f32x4 acc[4][4];
#pragma unroll
    for (int gt = 0; gt < 4; ++gt)
#pragma unroll
      for (int bt = 0; bt < 4; ++bt) acc[gt][bt] = {0.f, 0.f, 0.f, 0.f};
    int ksmax = (s == 0) ? 4 : 12;  // step 0: hq/r zero — only q contributes
    for (int ks = 0; ks < ksmax; ++ks) {
      const unsigned short* wk = wptr + (size_t)ks * SL;
      bf16x8 bfrag[4];
#pragma unroll
      for (int gt = 0; gt < 4; ++gt) bfrag[gt] = *(const bf16x8*)(wk + gt * 512);
      bf16x8 afrag[4];
#pragma unroll
      for (int bt = 0; bt < 4; ++bt)
        afrag[bt] = *(const bf16x8*)&sA[bt * 16 + l15][ks * 32 + l4 * 8];
#pragma unroll
      for (int gt = 0; gt < 4; ++gt)
#pragma unroll
        for (int bt = 0; bt < 4; ++bt)
          acc[gt][bt] = __builtin_amdgcn_mfma_f32_16x16x32_bf16(
              bfrag[gt], afrag[bt], acc[gt][bt], 0, 0, 0);
    }
    __syncthreads();  // GEMM reads of sA done before hq overwrite

    // ---- EW: acc f32x4 IS (i,f,g,o) for (row=bt*16+l15, j=w16+gt*4+l4) ----
#pragma unroll
    for (int gt = 0; gt < 4; ++gt) {
      int j = w16 + gt * 4 + l4;
      f32x4 bi = *(const f32x4*)&sBias[4 * j];
#pragma unroll
      for (int bt = 0; bt < 4; ++bt) {
        int row = bt * 16 + l15;
        f32x4 g = acc[gt][bt];
        float gi = g[0] + bi[0];
        float gf = g[1] + bi[1];
        float gg = g[2] + bi[2];
        float go = g[3] + bi[3];
        float c_old = bf2f(sC[row][j]);
        float c_new = sigm(gf) * c_old + sigm(gi) * tanh_(gg);
        sC[row][j] = f2bf(c_new);
        float hl = sigm(go) * tanh_(c_new);
        float hqv = bf2f(sA[row][j]) + hl;  // q + h_lstm
        sA[row][128 + j] = f2bf(hqv);
      }
    }
    __syncthreads();

    // ---- ATTN: logits + softmax + r (vectorized, chunk-swizzled) ----
    if (s < STEPS - 1) {
      int arow = tid >> 3, part = tid & 7;
      int ck = ((part + arow) & 7) * 16;
      bf16x8 h0 = *(const bf16x8*)&sA[arow][128 + ck];
      bf16x8 h1 = *(const bf16x8*)&sA[arow][128 + ck + 8];
      float hv[16];
#pragma unroll
      for (int e = 0; e < 8; ++e) {
        hv[e] = bf2f((unsigned short)h0[e]);
        hv[8 + e] = bf2f((unsigned short)h1[e]);
      }
      float lg[FEW];
#pragma unroll
      for (int ss = 0; ss < FEW; ++ss) {
        float a = 0.f;
#pragma unroll
        for (int e4 = 0; e4 < 4; ++e4) {
          f32x4 sv = *(const f32x4*)&sSg[ss][ck + e4 * 4];
          a += hv[e4 * 4 + 0] * sv[0] + hv[e4 * 4 + 1] * sv[1] +
               hv[e4 * 4 + 2] * sv[2] + hv[e4 * 4 + 3] * sv[3];
        }
        lg[ss] = a;
      }
#pragma unroll
      for (int off = 1; off < 8; off <<= 1)
#pragma unroll
        for (int ss = 0; ss < FEW; ++ss) lg[ss] += __shfl_xor(lg[ss], off, 64);
      float m = lg[0];
#pragma unroll
      for (int ss = 1; ss < FEW; ++ss) m = fmaxf(m, lg[ss]);
      float ev[FEW], tot = 0.f;
#pragma unroll
      for (int ss = 0; ss < FEW; ++ss) { ev[ss] = __expf(lg[ss] - m); tot += ev[ss]; }
      float inv = __builtin_amdgcn_rcpf(tot);
      bf16x8 r0, r1;
#pragma unroll
      for (int e = 0; e < 8; ++e) {
        int k0 = ck + e;
        int k1 = ck + 8 + e;
        float rv0 = 0.f, rv1 = 0.f;
#pragma unroll
        for (int ss = 0; ss < FEW; ++ss) {
          rv0 += ev[ss] * sSg[ss][k0];
          rv1 += ev[ss] * sSg[ss][k1];
        }
        r0[e] = (short)f2bf(rv0 * inv);
        r1[e] = (short)f2bf(rv1 * inv);
      }
      *(bf16x8*)&sA[arow][256 + ck] = r0;
      *(bf16x8*)&sA[arow][256 + ck + 8] = r1;
      __syncthreads();
    }
  }

  // ---- output: out[pair] = mean(hq[2p], hq[2p+1]) . mean_support ----
  int pair = tid >> 4, part = tid & 15;
  float accv = 0.f;
#pragma unroll
  for (int kk = 0; kk < 8; ++kk) {
    int k = part * 8 + kk;
    float h0 = bf2f(sA[2 * pair][128 + k]);
    float h1v = bf2f(sA[2 * pair + 1][128 + k]);
    accv += 0.5f * (h0 + h1v) * sMs[k];
  }
#pragma unroll
  for (int off = 1; off < 16; off <<= 1) accv += __shfl_xor(accv, off, 64);
  if (part == 0) out[blockIdx.x * 32 + pair] = accv;
}

extern "C" void kernel_launch(void* const* d_in, const int* in_sizes, int n_in,
                              void* d_out, int out_size, void* d_ws, size_t ws_size,
                              hipStream_t stream) {
  const int*   qp  = (const int*)d_in[0];
  const int*   sp  = (const int*)d_in[1];
  const float* emb = (const float*)d_in[2];
  const float* gw  = (const float*)d_in[3];
  const float* gb  = (const float*)d_in[4];
  const float* p1w = (const float*)d_in[5];
  const float* p1b = (const float*)d_in[6];
  const float* p2w = (const float*)d_in[7];
  const float* p2b = (const float*)d_in[8];
  const float* lng = (const float*)d_in[9];
  const float* lnb = (const float*)d_in[10];
  const float* wih = (const float*)d_in[11];
  const float* whh = (const float*)d_in[12];
  const float* bih = (const float*)d_in[13];
  const float* bhh = (const float*)d_in[14];
  char* ws = (char*)d_ws;
  unsigned short* Wgp = (unsigned short*)(ws + WS_WGP);
  float* bp   = (float*)(ws + WS_BP);
  float* sg   = (float*)(ws + WS_SG);
  float* ms   = (float*)(ws + WS_MS);
  float* part = (float*)(ws + WS_PART);
  float* out  = (float*)d_out;

  hipLaunchKernelGGL(prep_and_gather, dim3(768 + FEW * JCH), dim3(256), 0, stream,
                     wih, whh, bih, bhh, sp, emb, Wgp, bp, part);
  hipLaunchKernelGGL(support_kernel, dim3(1), dim3(256), 0, stream,
                     part, gw, gb, p1w, p1b, p2w, p2b, lng, lnb, sg, ms);
  hipLaunchKernelGGL(fused_query, dim3(NROWS / MROWS), dim3(512), 0, stream,
                     qp, emb, Wgp, bp, sg, ms, out);
}